// Round 3
// baseline (351.436 us; speedup 1.0000x reference)
//
#include <hip/hip_runtime.h>
#include <math.h>

#define B_ 4096
#define F_ 24
#define C_ 32      // floats per emb row (128 B)

// One 64-lane wave per batch row.
//   lane = g*8 + q :  q in [0,8) -> columns 4q..4q+3 (float4 of the 128B row)
//                     g in [0,8) -> field slot; field f = j*8 + g, j in 0..2
// One 64-lane dwordx4 load covers 8 gathered emb rows (1 KB) -> only 3 emb
// load instructions per wave (vs 12 in R2), 5 vmem instrs total.
// Power sums p1,p2,p3 per column, reduced over the g-dimension via
// shfl_xor(8,16,32); then e2 = (p1^2-p2)/2 on cols 0..15 (q<4),
// e3 = (p1^3-3p1p2+2p3)/6 on cols 16..31 (q>=4). Newton's identities,
// validated in R1/R2.
__global__ __launch_bounds__(256) void fm_ho_kernel(
    const int*   __restrict__ x,
    const int*   __restrict__ offsets,
    const float* __restrict__ w_linear,
    const float* __restrict__ bias,
    const float* __restrict__ emb,
    float*       __restrict__ out)
{
    const int tid  = threadIdx.x;
    const int lane = tid & 63;
    const int wave = tid >> 6;
    const int b    = blockIdx.x * 4 + wave;

    const int q = lane & 7;    // column quad: columns 4q..4q+3
    const int g = lane >> 3;   // field slot

    // Lanes 0..23 own one field each: gather index + w_linear (issues early).
    const int lf   = (lane < F_) ? lane : 0;
    const int idxl = x[b * F_ + lf] + offsets[lf];
    const float wl = (lane < F_) ? w_linear[idxl] : 0.f;

    // Broadcast this lane's 3 field indices, then issue all 3 float4 gathers
    // back-to-back so they batch before any waitcnt.
    int rows[3];
    #pragma unroll
    for (int j = 0; j < 3; ++j)
        rows[j] = __shfl(idxl, j * 8 + g, 64);

    float4 v[3];
    #pragma unroll
    for (int j = 0; j < 3; ++j)
        v[j] = *(const float4*)(emb + (size_t)rows[j] * C_ + 4 * q);

    // Power sums for this lane's 4 columns over its 3 fields.
    float P[3][4] = {{0.f}};
    #pragma unroll
    for (int j = 0; j < 3; ++j) {
        const float tv[4] = {v[j].x, v[j].y, v[j].z, v[j].w};
        #pragma unroll
        for (int k = 0; k < 4; ++k) {
            const float t = tv[k];
            P[0][k] += t;
            P[1][k] += t * t;
            P[2][k] += t * t * t;
        }
    }

    // Reduce over the g-dimension (lanes q, 8+q, ..., 56+q): full 24-field
    // power sums per column, replicated across g.
    #pragma unroll
    for (int m = 8; m <= 32; m <<= 1)
        #pragma unroll
        for (int i = 0; i < 3; ++i)
            #pragma unroll
            for (int k = 0; k < 4; ++k)
                P[i][k] += __shfl_xor(P[i][k], m, 64);

    float term = 0.f;
    if (q < 4) {            // columns 0..15: order-2
        #pragma unroll
        for (int k = 0; k < 4; ++k)
            term += P[0][k] * P[0][k] - P[1][k];
        term *= 0.5f;
    } else {                // columns 16..31: order-3
        #pragma unroll
        for (int k = 0; k < 4; ++k)
            term += P[0][k] * P[0][k] * P[0][k]
                  - 3.f * P[0][k] * P[1][k] + 2.f * P[2][k];
        term *= (1.0f / 6.0f);
    }

    // Count each column-term once (g==0 copy) + linear part on lanes 0..23.
    float contrib = wl + ((g == 0) ? term : 0.f);
    #pragma unroll
    for (int off = 32; off > 0; off >>= 1)
        contrib += __shfl_xor(contrib, off, 64);

    if (lane == 0)
        out[b] = 1.0f / (1.0f + __expf(-(contrib + bias[0])));
}

extern "C" void kernel_launch(void* const* d_in, const int* in_sizes, int n_in,
                              void* d_out, int out_size, void* d_ws, size_t ws_size,
                              hipStream_t stream) {
    const int*   x       = (const int*)  d_in[0];
    const int*   offsets = (const int*)  d_in[1];
    const float* w       = (const float*)d_in[2];
    const float* bias    = (const float*)d_in[3];
    const float* emb     = (const float*)d_in[4];
    float*       out     = (float*)      d_out;

    // 1 wave per row, 4 waves per block -> 1024 blocks, 4096 waves (16/CU)
    fm_ho_kernel<<<B_ / 4, 256, 0, stream>>>(x, offsets, w, bias, emb, out);
}